// Round 6
// baseline (75.008 us; speedup 1.0000x reference)
//
#include <hip/hip_runtime.h>
#include <hip/hip_fp16.h>
#include <math.h>

#define SEQ 250
#define NCLS 12

// Butterfly add via DPP within 16-lane rows (zero DS-pipe ops).
// 0xB1=quad_perm(1,0,3,2) xor1; 0x4E=quad_perm(2,3,0,1) xor2;
// 0x141=row_half_mirror (lane^7, valid once quad-constant);
// 0x140=row_mirror (lane^15, valid once 8-group-constant).
template<int CTRL>
__device__ __forceinline__ float dpp_add(float v) {
    int t = __builtin_amdgcn_update_dpp(0, __float_as_int(v), CTRL, 0xF, 0xF, true);
    return v + __int_as_float(t);
}

// One block per batch element, 256 threads.
// LDS: s_bc 16000 + s_dlu 16000 + s_u 8000 = 40,000 B -> 4 blocks/CU (16 waves
// = 4 waves/EU). Pin waves_per_eu to (4,4): LDS already caps residency at 4
// blocks/CU, so targeting 8 waves/EU (VGPR=64) only causes scratch spills of
// the sz registers (r4/r5 showed 46 MB of scratch writes).
__global__ __launch_bounds__(256)
__attribute__((amdgpu_waves_per_eu(4, 4)))
void mamba_cls_kernel(
    const float* __restrict__ x,         // (B, 8, 250)
    const float* __restrict__ in_proj_w, // (32, 8)
    const float* __restrict__ conv_w,    // (16, 4)
    const float* __restrict__ conv_b,    // (16)
    const float* __restrict__ x_proj_w,  // (33, 16)
    const float* __restrict__ dt_proj_w, // (16, 1)
    const float* __restrict__ dt_proj_b, // (16)
    const float* __restrict__ A_log,     // (16, 16)
    const float* __restrict__ Dp,        // (16)
    const float* __restrict__ out_proj_w,// (8, 16)
    const float* __restrict__ fc_w,      // (12, 2000)
    const float* __restrict__ fc_b,      // (12)
    float* __restrict__ out)             // (B, 12)
{
    // s_bc : ph1 x_in (f32 view [t*16+d]); ph3+ {B,C} half2 [t*16+s];
    //        ph5b+ out2000 (f32 view [t*8+j])
    // s_dlu: ph3+ {dl,dl*u} half2 [t*16+s]; ph4+ y (f32 view, same word); ph6 partials
    // s_u  : ph0-1 staged x (f32 view, 2000 floats); ph2+ u fp16 [t*16+d]
    __shared__ __align__(16) __half2 s_bc [SEQ * 16];
    __shared__ __align__(16) __half2 s_dlu[SEQ * 16];
    __shared__ __align__(16) __half  s_u  [SEQ * 16];

    const int b   = blockIdx.x;
    const int tid = threadIdx.x;
    float* s_f  = (float*)s_bc;
    float* s_y  = (float*)s_dlu;
    float* s_xf = (float*)s_u;

    // ---- Phase 0: stage x coalesced into the (future) u region
    {
        const float* __restrict__ xb = x + (size_t)b * (8 * SEQ);
        for (int i = tid; i < 8 * SEQ; i += 256) s_xf[i] = xb[i];
    }
    __syncthreads();

    // ---- Phase 1: x_in[t,d] -> s_f ; silu(z) packed fp16 -> 8 registers
    __half2 szp[8];
    {
        const int d  = tid & 15;
        const int t0 = tid >> 4;
        float w1[8], w2[8];
        #pragma unroll
        for (int m = 0; m < 8; ++m) {
            w1[m] = in_proj_w[d * 8 + m];
            w2[m] = in_proj_w[(16 + d) * 8 + m];
        }
        float sz_even = 0.f;
        #pragma unroll
        for (int i = 0; i < 16; ++i) {
            int t = t0 + i * 16;
            float sz = 0.f;
            if (t < SEQ) {
                float acc = 0.f, z = 0.f;
                #pragma unroll
                for (int m = 0; m < 8; ++m) {
                    float xv = s_xf[m * SEQ + t];
                    acc = fmaf(w1[m], xv, acc);
                    z   = fmaf(w2[m], xv, z);
                }
                s_f[t * 16 + d] = acc;
                sz = z / (1.f + __expf(-z));
            }
            if (i & 1) szp[i >> 1] = __floats2half2_rn(sz_even, sz);
            else       sz_even = sz;
        }
    }
    __syncthreads();

    // ---- Phase 2: causal conv(k=4)+SiLU -> u fp16 (overwrites dead x staging)
    {
        const int d  = tid & 15;
        const int t0 = tid >> 4;
        float cw[4];
        #pragma unroll
        for (int k = 0; k < 4; ++k) cw[k] = conv_w[d * 4 + k];
        const float cb = conv_b[d];
        #pragma unroll
        for (int i = 0; i < 16; ++i) {
            int t = t0 + i * 16;
            if (t < SEQ) {
                float acc = cb;
                #pragma unroll
                for (int k = 0; k < 4; ++k) {
                    int tt = t + k - 3;
                    if (tt >= 0) acc = fmaf(cw[k], s_f[tt * 16 + d], acc);
                }
                float sg = 1.f / (1.f + __expf(-acc));
                s_u[t * 16 + d] = __float2half(acc * sg);
            }
        }
    }
    __syncthreads();

    // ---- Phase 3: {B,C} -> s_bc ; {dl, dl*u} -> s_dlu (dt redundant per s-lane)
    {
        const int s = tid & 15;
        __half2 wb2[8], wc2[8], wd2[8];
        #pragma unroll
        for (int k = 0; k < 8; ++k) {
            wb2[k] = __floats2half2_rn(x_proj_w[(1 + s) * 16 + 2 * k],
                                       x_proj_w[(1 + s) * 16 + 2 * k + 1]);
            wc2[k] = __floats2half2_rn(x_proj_w[(17 + s) * 16 + 2 * k],
                                       x_proj_w[(17 + s) * 16 + 2 * k + 1]);
            wd2[k] = __floats2half2_rn(x_proj_w[2 * k], x_proj_w[2 * k + 1]);
        }
        const float dws = dt_proj_w[s];
        const float dbs = dt_proj_b[s];
        const __half2 zero2 = __float2half2_rn(0.f);
        for (int t = tid >> 4; t < SEQ; t += 16) {
            const __half2* up = (const __half2*)(s_u + t * 16);
            __half2 ab = zero2, ac = zero2, ad = zero2;
            #pragma unroll
            for (int k = 0; k < 8; ++k) {
                __half2 uv = up[k];
                ab = __hfma2(uv, wb2[k], ab);
                ac = __hfma2(uv, wc2[k], ac);
                ad = __hfma2(uv, wd2[k], ad);
            }
            float abf = __half2float(__low2half(ab)) + __half2float(__high2half(ab));
            float acf = __half2float(__low2half(ac)) + __half2float(__high2half(ac));
            float adf = __half2float(__low2half(ad)) + __half2float(__high2half(ad));
            s_bc[t * 16 + s] = __floats2half2_rn(abf, acf);
            float v  = fmaf(adf, dws, dbs);
            float dl = (v > 20.f) ? v : __logf(1.f + __expf(v));
            float uf = __half2float(s_u[t * 16 + s]);
            s_dlu[t * 16 + s] = __floats2half2_rn(dl, dl * uf);
        }
    }
    __syncthreads();

    // ---- Phase 4: scan. thread = (d = tid>>4, s = tid&15); 2 LDS reads per t.
    {
        const int d = tid >> 4;
        const int s = tid & 15;
        const float A2 = -__expf(A_log[d * 16 + s]) * 1.4426950408889634f;
        float h = 0.f;
        #pragma unroll 5
        for (int t = 0; t < SEQ; ++t) {
            float2 dlu = __half22float2(s_dlu[t * 16 + d]);  // {dl, dl*u} bcast over s
            float2 bc  = __half22float2(s_bc [t * 16 + s]);  // {B, C}    bcast over d
            float dA = exp2f(dlu.x * A2);
            h = fmaf(dA, h, dlu.y * bc.x);
            float r = h * bc.y;
            r = dpp_add<0xB1>(r);
            r = dpp_add<0x4E>(r);
            r = dpp_add<0x141>(r);
            r = dpp_add<0x140>(r);
            if (s == 0) s_y[t * 16 + d] = r;   // y_raw over the dead {dl,dlu} word
        }
    }
    __syncthreads();

    // ---- Phase 5: y = (y_raw + u*D) * silu(z)   (sz unpacked from szp regs)
    {
        const int d  = tid & 15;
        const int t0 = tid >> 4;
        const float Dd = Dp[d];
        #pragma unroll
        for (int i = 0; i < 16; ++i) {
            int t = t0 + i * 16;
            if (t < SEQ) {
                float2 szv = __half22float2(szp[i >> 1]);
                float sz = (i & 1) ? szv.y : szv.x;
                float uf = __half2float(s_u[t * 16 + d]);
                s_y[t * 16 + d] = fmaf(uf, Dd, s_y[t * 16 + d]) * sz;
            }
        }
    }
    __syncthreads();

    // ---- Phase 5b: out2000[t*8+j] = sum_d y[t,d]*out_proj_w[j,d] (into s_f)
    {
        const int j = tid & 7;
        float w[16];
        #pragma unroll
        for (int d2 = 0; d2 < 16; ++d2) w[d2] = out_proj_w[j * 16 + d2];
        for (int t = tid >> 3; t < SEQ; t += 32) {
            float a = 0.f;
            #pragma unroll
            for (int d2 = 0; d2 < 16; ++d2) a = fmaf(w[d2], s_y[t * 16 + d2], a);
            s_f[t * 8 + j] = a;
        }
    }
    __syncthreads();

    // ---- Phase 6: logits[c] = out2000 . fc_w[c,:] + fc_b[c]  (float4 loads)
    {
        float p[NCLS];
        #pragma unroll
        for (int c = 0; c < NCLS; ++c) p[c] = 0.f;
        const float4* fw4 = (const float4*)fc_w;
        const float4* sf4 = (const float4*)s_f;
        for (int q = tid; q < 500; q += 256) {
            float4 f = sf4[q];
            #pragma unroll
            for (int c = 0; c < NCLS; ++c) {
                float4 wv = fw4[c * 500 + q];
                p[c] += f.x * wv.x + f.y * wv.y + f.z * wv.z + f.w * wv.w;
            }
        }
        #pragma unroll
        for (int c = 0; c < NCLS; ++c) {
            float v = p[c];
            v = dpp_add<0xB1>(v);
            v = dpp_add<0x4E>(v);
            v = dpp_add<0x141>(v);
            v = dpp_add<0x140>(v);
            v += __shfl_xor(v, 16);
            v += __shfl_xor(v, 32);
            p[c] = v;
        }
        const int wave = tid >> 6;
        const int lane = tid & 63;
        if (lane == 0) {
            #pragma unroll
            for (int c = 0; c < NCLS; ++c) s_y[wave * NCLS + c] = p[c];
        }
        __syncthreads();
        if (tid < NCLS) {
            float v = s_y[tid] + s_y[NCLS + tid] + s_y[2 * NCLS + tid] +
                      s_y[3 * NCLS + tid] + fc_b[tid];
            out[(size_t)b * NCLS + tid] = v;
        }
    }
}

extern "C" void kernel_launch(void* const* d_in, const int* in_sizes, int n_in,
                              void* d_out, int out_size, void* d_ws, size_t ws_size,
                              hipStream_t stream) {
    const float* x          = (const float*)d_in[0];
    const float* in_proj_w  = (const float*)d_in[1];
    const float* conv_w     = (const float*)d_in[2];
    const float* conv_b     = (const float*)d_in[3];
    const float* x_proj_w   = (const float*)d_in[4];
    const float* dt_proj_w  = (const float*)d_in[5];
    const float* dt_proj_b  = (const float*)d_in[6];
    const float* A_log      = (const float*)d_in[7];
    const float* Dp         = (const float*)d_in[8];
    const float* out_proj_w = (const float*)d_in[9];
    const float* fc_w       = (const float*)d_in[10];
    const float* fc_b       = (const float*)d_in[11];
    float* out = (float*)d_out;

    const int batch = in_sizes[0] / (8 * SEQ);  // 1024
    mamba_cls_kernel<<<batch, 256, 0, stream>>>(
        x, in_proj_w, conv_w, conv_b, x_proj_w, dt_proj_w, dt_proj_b,
        A_log, Dp, out_proj_w, fc_w, fc_b, out);
}